// Round 13
// baseline (143.259 us; speedup 1.0000x reference)
//
#include <hip/hip_runtime.h>

#define DIM 256
#define HID 64
#define HW 4096          // 64*64
#define LW 72            // LDS row stride (floats); per-row skew provides bank spread

typedef float f4 __attribute__((ext_vector_type(4)));

// skew(R) = ((R>>2) + G[R&3]) & 3, G={0,0,2,3}: stride-4 AND stride-1 row quadruples
// both hit 4 distinct mod-4 bank residue classes -> 32 banks, 2-way, conflict-free.
__device__ __forceinline__ int skew_of(int R) {
    int r3 = R & 3;
    int g = (r3 & 2) ? r3 : 0;
    return ((R >> 2) + g) & 3;
}

// ---------------- Kernel 1: pool (blocks 0..8191) + sig (blocks 8192..8223) ----------------
// Pool blocks: plane mean -> atomicExch(pooled[plane]) -> ordered atomicAdd(cnt[b]).
// Sig blocks (1/batch): spin on cnt[b]==256, atomic-read pooled row -> LDS,
// sig[t] = sigmoid(BN(dot(pooled[b], w1[t]))) -> sigg (read by conv next dispatch).
// Deadlock-free: 32 spinners << 2048 resident-block slots; pool blocks always progress.
__global__ __launch_bounds__(256) void pool_sig_kernel(const float* __restrict__ x,
                                                       const float* __restrict__ w1,
                                                       const float* __restrict__ gamma,
                                                       const float* __restrict__ beta,
                                                       const float* __restrict__ mean,
                                                       const float* __restrict__ var,
                                                       float* __restrict__ pooled,
                                                       float* __restrict__ sigg,
                                                       unsigned int* __restrict__ cnt) {
    int bid = blockIdx.x;
    int tid = threadIdx.x;
    __shared__ float ws[4];
    __shared__ __align__(16) float sp[DIM];

    if (bid < 8192) {
        // ---- pool role ----
        int plane = bid;
        const float4* p = (const float4*)(x + (size_t)plane * HW);
        float s = 0.f;
#pragma unroll
        for (int k = 0; k < 4; ++k) {
            float4 v = p[tid + k * 256];          // normal loads (allocate in L2/L3)
            s += (v.x + v.y) + (v.z + v.w);
        }
#pragma unroll
        for (int off = 32; off > 0; off >>= 1) s += __shfl_down(s, off, 64);
        int wid = tid >> 6, lane = tid & 63;
        if (lane == 0) ws[wid] = s;
        __syncthreads();
        if (tid == 0) {
            float t = (ws[0] + ws[1]) + (ws[2] + ws[3]);
            float val = t * (1.0f / (float)HW);
            // device-scope publish, then ordered counter increment
            float old = atomicExch(&pooled[plane], val);
            asm volatile("" :: "v"(old) : "memory");   // force vmcnt drain before cnt add
            atomicAdd(&cnt[plane >> 8], 1u);
        }
        return;
    }

    // ---- sig role: one block per batch ----
    int b = bid - 8192;
    if (tid == 0) {
        while (atomicAdd(&cnt[b], 0u) < 256u) { __builtin_amdgcn_s_sleep(2); }
    }
    __syncthreads();
    // atomic read-through of the batch's pooled row (device-coherent point)
    sp[tid] = atomicAdd(&pooled[b * DIM + tid], 0.0f);
    __syncthreads();
    if (tid < HID) {
        const f4* wr = (const f4*)(w1 + (size_t)tid * DIM);
        const f4* s4 = (const f4*)sp;
        float acc = 0.f;
#pragma unroll
        for (int i = 0; i < DIM / 4; ++i) {
            f4 v = wr[i], u_ = s4[i];
            acc += v.x * u_.x + v.y * u_.y + v.z * u_.z + v.w * u_.w;
        }
        float yb = (acc - mean[tid]) * rsqrtf(var[tid] + 1e-5f) * gamma[tid] + beta[tid];
        sigg[b * HID + tid] = 1.0f / (1.0f + expf(-yb));
    }
}

// ---------------- Kernel 2: depthwise 3x3 conv (R6-proven: forward order) ----------------
__global__ __launch_bounds__(256) void conv_kernel(const float* __restrict__ x,
                                                   const float* __restrict__ sigg,
                                                   const float* __restrict__ w2,
                                                   const float* __restrict__ b2,
                                                   const float* __restrict__ bias,
                                                   float* __restrict__ out) {
    int plane = blockIdx.x;                  // forward order (R12: reverse hurt)
    int c = plane & (DIM - 1);
    int b = plane >> 8;
    int tid = threadIdx.x;
    const float* xp = x + (size_t)plane * HW;

    __shared__ float lds[66 * LW];
    __shared__ float wsh[12];

    // 1) issue x loads first (longest latency); nt (single use)
    const f4* xp4 = (const f4*)xp;
    f4 st[4];
#pragma unroll
    for (int k = 0; k < 4; ++k) st[k] = __builtin_nontemporal_load(&xp4[tid + k * 256]);

    // 2) threads 0..8: this plane's 9 dyn taps from sigg + w2 slice (L2-resident)
    if (tid < 9) {
        int kk = c * 9 + tid;
        const float4* wk = (const float4*)(w2 + (size_t)kk * HID);
        const float4* sg = (const float4*)(sigg + b * HID);
        float acc = b2[kk];
#pragma unroll
        for (int i = 0; i < HID / 4; ++i) {
            float4 v = wk[i]; float4 u = sg[i];
            acc += v.x * u.x + v.y * u.y + v.z * u.z + v.w * u.w;
        }
        wsh[tid] = acc;
    }

    // 3) zero halo cells (disjoint from staged interior)
    for (int i = tid; i < 272; i += 256) {
        int addr;
        if (i < 72)        addr = i;
        else if (i < 144)  addr = 65 * LW + (i - 72);
        else {
            int z = i - 144;
            int R = 1 + (z >> 1);
            addr = R * LW + skew_of(R) + 3 + (z & 1) * 65;
        }
        lds[addr] = 0.f;
    }

    // 4) stage interior: skewed scalar writes (conflict-free, proven)
#pragma unroll
    for (int k = 0; k < 4; ++k) {
        int idx = tid + k * 256;
        int R = (idx >> 4) + 1;
        int col0 = (idx & 15) * 4;
        float* dst = &lds[R * LW + skew_of(R) + 4 + col0];
        dst[0] = st[k].x; dst[1] = st[k].y; dst[2] = st[k].z; dst[3] = st[k].w;
    }
    __syncthreads();

    // 5) weights + bias to regs
    float w[9];
#pragma unroll
    for (int i = 0; i < 9; ++i) w[i] = wsh[i];
    float bv = bias[c];

    // 6) 4x4 tile per thread, 6x6 LDS patch with vertical reuse
    int u = tid >> 4, j = tid & 15;
    float acc[4][4];
#pragma unroll
    for (int m = 0; m < 4; ++m)
#pragma unroll
        for (int i = 0; i < 4; ++i) acc[m][i] = bv;

#define FCT(m, t)                                                              \
    {                                                                          \
        float w0 = w[(t)*3 + 0], w1v = w[(t)*3 + 1], w2v = w[(t)*3 + 2];       \
        acc[m][0] += w0 * a0 + w1v * a1 + w2v * a2;                            \
        acc[m][1] += w0 * a1 + w1v * a2 + w2v * a3;                            \
        acc[m][2] += w0 * a2 + w1v * a3 + w2v * a4;                            \
        acc[m][3] += w0 * a3 + w1v * a4 + w2v * a5;                            \
    }
#define FRD(d)                                                                 \
    float a0, a1, a2, a3, a4, a5;                                              \
    {                                                                          \
        int R = 4 * u + (d);                                                   \
        const float* r = &lds[R * LW + skew_of(R) + 3 + 4 * j];                \
        a0 = r[0]; a1 = r[1]; a2 = r[2]; a3 = r[3]; a4 = r[4]; a5 = r[5];      \
    }

    { FRD(0) FCT(0, 0) }
    { FRD(1) FCT(0, 1) FCT(1, 0) }
    { FRD(2) FCT(0, 2) FCT(1, 1) FCT(2, 0) }
    { FRD(3) FCT(1, 2) FCT(2, 1) FCT(3, 0) }
    { FRD(4) FCT(2, 2) FCT(3, 1) }
    { FRD(5) FCT(3, 2) }
#undef FRD
#undef FCT

    // 7) store: nt (streaming output)
    f4* op4 = (f4*)(out + (size_t)plane * HW);
#pragma unroll
    for (int m = 0; m < 4; ++m) {
        f4 o;
        o.x = acc[m][0]; o.y = acc[m][1]; o.z = acc[m][2]; o.w = acc[m][3];
        __builtin_nontemporal_store(o, &op4[(4 * u + m) * 16 + j]);
    }
}

extern "C" void kernel_launch(void* const* d_in, const int* in_sizes, int n_in,
                              void* d_out, int out_size, void* d_ws, size_t ws_size,
                              hipStream_t stream) {
    const float* x     = (const float*)d_in[0];
    const float* w1    = (const float*)d_in[1];
    const float* gamma = (const float*)d_in[2];
    const float* beta  = (const float*)d_in[3];
    const float* mean  = (const float*)d_in[4];
    const float* var   = (const float*)d_in[5];
    const float* w2    = (const float*)d_in[6];
    const float* b2    = (const float*)d_in[7];
    const float* bias  = (const float*)d_in[8];
    float* out = (float*)d_out;

    float* pooled = (float*)d_ws;                      // 8192 floats
    float* sigg   = pooled + 8192;                     // 2048 floats
    unsigned int* cnt = (unsigned int*)(sigg + 2048);  // 32 uints

    hipMemsetAsync(cnt, 0, 32 * sizeof(unsigned int), stream);
    pool_sig_kernel<<<8224, 256, 0, stream>>>(x, w1, gamma, beta, mean, var,
                                              pooled, sigg, cnt);
    conv_kernel<<<8192, 256, 0, stream>>>(x, sigg, w2, b2, bias, out);
}

// Round 14
// 69.930 us; speedup vs baseline: 2.0486x; 2.0486x over previous
//
#include <hip/hip_runtime.h>

#define DIM 256
#define HID 64
#define HW 4096          // 64*64
#define LW 72            // LDS row stride (floats); per-row skew provides bank spread

typedef float f4 __attribute__((ext_vector_type(4)));

// skew(R) = ((R>>2) + G[R&3]) & 3, G={0,0,2,3}: stride-4 AND stride-1 row quadruples
// both hit 4 distinct mod-4 bank residue classes -> 32 banks, 2-way, conflict-free.
__device__ __forceinline__ int skew_of(int R) {
    int r3 = R & 3;
    int g = (r3 & 2) ? r3 : 0;
    return ((R >> 2) + g) & 3;
}

// ---------------- Kernel 1: global average pool over each (b,c) plane ----------------
// Normal (allocating) loads: leave x resident in L3 for the conv pass.
__global__ __launch_bounds__(256) void pool_kernel(const float* __restrict__ x,
                                                   float* __restrict__ pooled) {
    int plane = blockIdx.x;                       // b*DIM + c, 8192 planes
    const float4* p = (const float4*)(x + (size_t)plane * HW);
    int tid = threadIdx.x;
    float s = 0.f;
#pragma unroll
    for (int k = 0; k < 4; ++k) {
        float4 v = p[tid + k * 256];
        s += (v.x + v.y) + (v.z + v.w);
    }
#pragma unroll
    for (int off = 32; off > 0; off >>= 1) s += __shfl_down(s, off, 64);
    __shared__ float ws[4];
    int wid = tid >> 6, lane = tid & 63;
    if (lane == 0) ws[wid] = s;
    __syncthreads();
    if (tid == 0) {
        float t = (ws[0] + ws[1]) + (ws[2] + ws[3]);
        pooled[plane] = t * (1.0f / (float)HW);
    }
}

// ---------------- Kernel 2: sigmoid(BN(pooled @ w1^T)) -> sig[32][64] ----------------
__global__ __launch_bounds__(64) void sig_kernel(const float* __restrict__ pooled,
                                                 const float* __restrict__ w1,
                                                 const float* __restrict__ gamma,
                                                 const float* __restrict__ beta,
                                                 const float* __restrict__ mean,
                                                 const float* __restrict__ var,
                                                 float* __restrict__ sigg) {
    int b = blockIdx.x;              // 32 blocks
    int t = threadIdx.x;             // 64 threads
    __shared__ float sp[DIM];
    ((float4*)sp)[t] = ((const float4*)(pooled + b * DIM))[t];
    __syncthreads();
    const float4* wr = (const float4*)(w1 + t * DIM);
    const float4* s4 = (const float4*)sp;
    float acc = 0.f;
#pragma unroll
    for (int i = 0; i < DIM / 4; ++i) {
        float4 v = wr[i]; float4 u = s4[i];
        acc += v.x * u.x + v.y * u.y + v.z * u.z + v.w * u.w;
    }
    float yb = (acc - mean[t]) * rsqrtf(var[t] + 1e-5f) * gamma[t] + beta[t];
    sigg[b * HID + t] = 1.0f / (1.0f + expf(-yb));
}

// ---------------- Kernel 3: depthwise 3x3 conv, forward order ----------------
// PLAIN x loads (probe L3: R11 showed ~50% of x is retained; nt bits would bypass it).
// nt out stores (streaming output; don't evict x from L3).
__global__ __launch_bounds__(256) void conv_kernel(const float* __restrict__ x,
                                                   const float* __restrict__ sigg,
                                                   const float* __restrict__ w2,
                                                   const float* __restrict__ b2,
                                                   const float* __restrict__ bias,
                                                   float* __restrict__ out) {
    int plane = blockIdx.x;                  // forward order (R12: reverse hurt)
    int c = plane & (DIM - 1);
    int b = plane >> 8;
    int tid = threadIdx.x;
    const float* xp = x + (size_t)plane * HW;

    __shared__ float lds[66 * LW];
    __shared__ float wsh[12];

    // 1) issue x loads first (longest latency); PLAIN loads -> L3 can serve them
    const f4* xp4 = (const f4*)xp;
    f4 st[4];
#pragma unroll
    for (int k = 0; k < 4; ++k) st[k] = xp4[tid + k * 256];

    // 2) threads 0..8: this plane's 9 dyn taps from sigg + w2 slice (L2-resident)
    if (tid < 9) {
        int kk = c * 9 + tid;
        const float4* wk = (const float4*)(w2 + (size_t)kk * HID);
        const float4* sg = (const float4*)(sigg + b * HID);
        float acc = b2[kk];
#pragma unroll
        for (int i = 0; i < HID / 4; ++i) {
            float4 v = wk[i]; float4 u = sg[i];
            acc += v.x * u.x + v.y * u.y + v.z * u.z + v.w * u.w;
        }
        wsh[tid] = acc;
    }

    // 3) zero halo cells (disjoint from staged interior)
    for (int i = tid; i < 272; i += 256) {
        int addr;
        if (i < 72)        addr = i;
        else if (i < 144)  addr = 65 * LW + (i - 72);
        else {
            int z = i - 144;
            int R = 1 + (z >> 1);
            addr = R * LW + skew_of(R) + 3 + (z & 1) * 65;
        }
        lds[addr] = 0.f;
    }

    // 4) stage interior: skewed scalar writes (conflict-free, proven)
#pragma unroll
    for (int k = 0; k < 4; ++k) {
        int idx = tid + k * 256;
        int R = (idx >> 4) + 1;
        int col0 = (idx & 15) * 4;
        float* dst = &lds[R * LW + skew_of(R) + 4 + col0];
        dst[0] = st[k].x; dst[1] = st[k].y; dst[2] = st[k].z; dst[3] = st[k].w;
    }
    __syncthreads();

    // 5) weights + bias to regs
    float w[9];
#pragma unroll
    for (int i = 0; i < 9; ++i) w[i] = wsh[i];
    float bv = bias[c];

    // 6) 4x4 tile per thread, 6x6 LDS patch with vertical reuse
    int u = tid >> 4, j = tid & 15;
    float acc[4][4];
#pragma unroll
    for (int m = 0; m < 4; ++m)
#pragma unroll
        for (int i = 0; i < 4; ++i) acc[m][i] = bv;

#define FCT(m, t)                                                              \
    {                                                                          \
        float w0 = w[(t)*3 + 0], w1v = w[(t)*3 + 1], w2v = w[(t)*3 + 2];       \
        acc[m][0] += w0 * a0 + w1v * a1 + w2v * a2;                            \
        acc[m][1] += w0 * a1 + w1v * a2 + w2v * a3;                            \
        acc[m][2] += w0 * a2 + w1v * a3 + w2v * a4;                            \
        acc[m][3] += w0 * a3 + w1v * a4 + w2v * a5;                            \
    }
#define FRD(d)                                                                 \
    float a0, a1, a2, a3, a4, a5;                                              \
    {                                                                          \
        int R = 4 * u + (d);                                                   \
        const float* r = &lds[R * LW + skew_of(R) + 3 + 4 * j];                \
        a0 = r[0]; a1 = r[1]; a2 = r[2]; a3 = r[3]; a4 = r[4]; a5 = r[5];      \
    }

    { FRD(0) FCT(0, 0) }
    { FRD(1) FCT(0, 1) FCT(1, 0) }
    { FRD(2) FCT(0, 2) FCT(1, 1) FCT(2, 0) }
    { FRD(3) FCT(1, 2) FCT(2, 1) FCT(3, 0) }
    { FRD(4) FCT(2, 2) FCT(3, 1) }
    { FRD(5) FCT(3, 2) }
#undef FRD
#undef FCT

    // 7) store: nt (streaming output; don't evict x)
    f4* op4 = (f4*)(out + (size_t)plane * HW);
#pragma unroll
    for (int m = 0; m < 4; ++m) {
        f4 o;
        o.x = acc[m][0]; o.y = acc[m][1]; o.z = acc[m][2]; o.w = acc[m][3];
        __builtin_nontemporal_store(o, &op4[(4 * u + m) * 16 + j]);
    }
}

extern "C" void kernel_launch(void* const* d_in, const int* in_sizes, int n_in,
                              void* d_out, int out_size, void* d_ws, size_t ws_size,
                              hipStream_t stream) {
    const float* x     = (const float*)d_in[0];
    const float* w1    = (const float*)d_in[1];
    const float* gamma = (const float*)d_in[2];
    const float* beta  = (const float*)d_in[3];
    const float* mean  = (const float*)d_in[4];
    const float* var   = (const float*)d_in[5];
    const float* w2    = (const float*)d_in[6];
    const float* b2    = (const float*)d_in[7];
    const float* bias  = (const float*)d_in[8];
    float* out = (float*)d_out;

    float* pooled = (float*)d_ws;            // 8192 floats
    float* sigg = pooled + 8192;             // 32*64 floats

    pool_kernel<<<8192, 256, 0, stream>>>(x, pooled);
    sig_kernel<<<32, 64, 0, stream>>>(pooled, w1, gamma, beta, mean, var, sigg);
    conv_kernel<<<8192, 256, 0, stream>>>(x, sigg, w2, b2, bias, out);
}

// Round 15
// 68.440 us; speedup vs baseline: 2.0932x; 1.0218x over previous
//
#include <hip/hip_runtime.h>

#define DIM 256
#define HID 64
#define HW 4096          // 64*64
#define LW 72            // LDS row stride (floats); per-row skew provides bank spread

typedef float f4 __attribute__((ext_vector_type(4)));

// skew(R) = ((R>>2) + G[R&3]) & 3, G={0,0,2,3}: stride-4 AND stride-1 row quadruples
// both hit 4 distinct mod-4 bank residue classes -> 32 banks, 2-way, conflict-free.
__device__ __forceinline__ int skew_of(int R) {
    int r3 = R & 3;
    int g = (r3 & 2) ? r3 : 0;
    return ((R >> 2) + g) & 3;
}

// ---------------- Kernel 1: global average pool over each (b,c) plane ----------------
__global__ __launch_bounds__(256) void pool_kernel(const float* __restrict__ x,
                                                   float* __restrict__ pooled) {
    int plane = blockIdx.x;                       // b*DIM + c, 8192 planes
    const float4* p = (const float4*)(x + (size_t)plane * HW);
    int tid = threadIdx.x;
    float s = 0.f;
#pragma unroll
    for (int k = 0; k < 4; ++k) {
        float4 v = p[tid + k * 256];
        s += (v.x + v.y) + (v.z + v.w);
    }
#pragma unroll
    for (int off = 32; off > 0; off >>= 1) s += __shfl_down(s, off, 64);
    __shared__ float ws[4];
    int wid = tid >> 6, lane = tid & 63;
    if (lane == 0) ws[wid] = s;
    __syncthreads();
    if (tid == 0) {
        float t = (ws[0] + ws[1]) + (ws[2] + ws[3]);
        pooled[plane] = t * (1.0f / (float)HW);
    }
}

// ---------------- Kernel 2: sigmoid(BN(pooled @ w1^T)) -> sig[32][64] ----------------
__global__ __launch_bounds__(64) void sig_kernel(const float* __restrict__ pooled,
                                                 const float* __restrict__ w1,
                                                 const float* __restrict__ gamma,
                                                 const float* __restrict__ beta,
                                                 const float* __restrict__ mean,
                                                 const float* __restrict__ var,
                                                 float* __restrict__ sigg) {
    int b = blockIdx.x;              // 32 blocks
    int t = threadIdx.x;             // 64 threads
    __shared__ float sp[DIM];
    ((float4*)sp)[t] = ((const float4*)(pooled + b * DIM))[t];
    __syncthreads();
    const float4* wr = (const float4*)(w1 + t * DIM);
    const float4* s4 = (const float4*)sp;
    float acc = 0.f;
#pragma unroll
    for (int i = 0; i < DIM / 4; ++i) {
        float4 v = wr[i]; float4 u = s4[i];
        acc += v.x * u.x + v.y * u.y + v.z * u.z + v.w * u.w;
    }
    float yb = (acc - mean[t]) * rsqrtf(var[t] + 1e-5f) * gamma[t] + beta[t];
    sigg[b * HID + t] = 1.0f / (1.0f + expf(-yb));
}

// ---------------- Kernel 3: depthwise 3x3 conv, 4x4 outputs/thread, in-block dyn-gen ----------------
__global__ __launch_bounds__(256) void conv_kernel(const float* __restrict__ x,
                                                   const float* __restrict__ sigg,
                                                   const float* __restrict__ w2,
                                                   const float* __restrict__ b2,
                                                   const float* __restrict__ bias,
                                                   float* __restrict__ out) {
    int plane = blockIdx.x;                  // forward order (best measured)
    int c = plane & (DIM - 1);
    int b = plane >> 8;
    int tid = threadIdx.x;
    const float* xp = x + (size_t)plane * HW;

    __shared__ float lds[66 * LW];
    __shared__ float wsh[12];

    // 1) issue x global loads first (longest latency); nt (single use)
    const f4* xp4 = (const f4*)xp;
    f4 st[4];
#pragma unroll
    for (int k = 0; k < 4; ++k) st[k] = __builtin_nontemporal_load(&xp4[tid + k * 256]);

    // 2) threads 0..8 generate this plane's 9 dyn weights from sig (L2-resident w2 slice)
    if (tid < 9) {
        int kk = c * 9 + tid;
        const float4* wk = (const float4*)(w2 + (size_t)kk * HID);
        const float4* sg = (const float4*)(sigg + b * HID);
        float acc = b2[kk];
#pragma unroll
        for (int i = 0; i < HID / 4; ++i) {
            float4 v = wk[i]; float4 u = sg[i];
            acc += v.x * u.x + v.y * u.y + v.z * u.z + v.w * u.w;
        }
        wsh[tid] = acc;
    }

    // 3) zero halo cells (disjoint from staged interior)
    for (int i = tid; i < 272; i += 256) {
        int addr;
        if (i < 72)        addr = i;
        else if (i < 144)  addr = 65 * LW + (i - 72);
        else {
            int z = i - 144;
            int R = 1 + (z >> 1);
            addr = R * LW + skew_of(R) + 3 + (z & 1) * 65;
        }
        lds[addr] = 0.f;
    }

    // 4) stage interior: skewed scalar writes (conflict-free)
#pragma unroll
    for (int k = 0; k < 4; ++k) {
        int idx = tid + k * 256;
        int R = (idx >> 4) + 1;
        int col0 = (idx & 15) * 4;
        float* dst = &lds[R * LW + skew_of(R) + 4 + col0];
        dst[0] = st[k].x; dst[1] = st[k].y; dst[2] = st[k].z; dst[3] = st[k].w;
    }
    __syncthreads();

    // 5) weights + bias to regs
    float w[9];
#pragma unroll
    for (int i = 0; i < 9; ++i) w[i] = wsh[i];
    float bv = bias[c];

    // 6) 4x4 tile per thread, 6x6 LDS patch with vertical reuse
    int u = tid >> 4, j = tid & 15;
    float acc[4][4];
#pragma unroll
    for (int m = 0; m < 4; ++m)
#pragma unroll
        for (int i = 0; i < 4; ++i) acc[m][i] = bv;

#define FCT(m, t)                                                              \
    {                                                                          \
        float w0 = w[(t)*3 + 0], w1v = w[(t)*3 + 1], w2v = w[(t)*3 + 2];       \
        acc[m][0] += w0 * a0 + w1v * a1 + w2v * a2;                            \
        acc[m][1] += w0 * a1 + w1v * a2 + w2v * a3;                            \
        acc[m][2] += w0 * a2 + w1v * a3 + w2v * a4;                            \
        acc[m][3] += w0 * a3 + w1v * a4 + w2v * a5;                            \
    }
#define FRD(d)                                                                 \
    float a0, a1, a2, a3, a4, a5;                                              \
    {                                                                          \
        int R = 4 * u + (d);                                                   \
        const float* r = &lds[R * LW + skew_of(R) + 3 + 4 * j];                \
        a0 = r[0]; a1 = r[1]; a2 = r[2]; a3 = r[3]; a4 = r[4]; a5 = r[5];      \
    }

    { FRD(0) FCT(0, 0) }
    { FRD(1) FCT(0, 1) FCT(1, 0) }
    { FRD(2) FCT(0, 2) FCT(1, 1) FCT(2, 0) }
    { FRD(3) FCT(1, 2) FCT(2, 1) FCT(3, 0) }
    { FRD(4) FCT(2, 2) FCT(3, 1) }
    { FRD(5) FCT(3, 2) }
#undef FRD
#undef FCT

    // 7) store: nt (streaming output)
    f4* op4 = (f4*)(out + (size_t)plane * HW);
#pragma unroll
    for (int m = 0; m < 4; ++m) {
        f4 o;
        o.x = acc[m][0]; o.y = acc[m][1]; o.z = acc[m][2]; o.w = acc[m][3];
        __builtin_nontemporal_store(o, &op4[(4 * u + m) * 16 + j]);
    }
}

extern "C" void kernel_launch(void* const* d_in, const int* in_sizes, int n_in,
                              void* d_out, int out_size, void* d_ws, size_t ws_size,
                              hipStream_t stream) {
    const float* x     = (const float*)d_in[0];
    const float* w1    = (const float*)d_in[1];
    const float* gamma = (const float*)d_in[2];
    const float* beta  = (const float*)d_in[3];
    const float* mean  = (const float*)d_in[4];
    const float* var   = (const float*)d_in[5];
    const float* w2    = (const float*)d_in[6];
    const float* b2    = (const float*)d_in[7];
    const float* bias  = (const float*)d_in[8];
    float* out = (float*)d_out;

    float* pooled = (float*)d_ws;            // 8192 floats
    float* sigg = pooled + 8192;             // 32*64 floats

    pool_kernel<<<8192, 256, 0, stream>>>(x, pooled);
    sig_kernel<<<32, 64, 0, stream>>>(pooled, w1, gamma, beta, mean, var, sigg);
    conv_kernel<<<8192, 256, 0, stream>>>(x, sigg, w2, b2, bias, out);
}